// Round 1
// baseline (190.590 us; speedup 1.0000x reference)
//
#include <hip/hip_runtime.h>

// Problem: K=128 users, M=1024, N=C=128.
// Step 1 (HBM-bound, 134 MB): h[k,m] = h_d[k,m] + sum_n A[k,m,n]*v[n]  (complex)
// Step 2 (tiny): g = h @ W (complex, 128x1024 @ 1024x128), then SINR reduction.

#define KM_ROWS (128 * 1024)

__global__ __launch_bounds__(256) void compute_h_kernel(
    const float* __restrict__ A_real,
    const float* __restrict__ A_imag,
    const float* __restrict__ W_v,       // row 0 = v (256 floats: v_re | v_im)
    const float* __restrict__ h_d_real,
    const float* __restrict__ h_d_imag,
    float* __restrict__ h_re,
    float* __restrict__ h_im)
{
    const int lane = threadIdx.x & 63;
    const int wave = threadIdx.x >> 6;
    const int subl = lane & 31;                       // 32 lanes per row
    const int row  = (blockIdx.x * 4 + wave) * 2 + (lane >> 5); // 0..131071

    // 32 lanes x float4 = 128 floats = one row of A[k,m,:]
    const float4 ar = ((const float4*)(A_real + (size_t)row * 128))[subl];
    const float4 ai = ((const float4*)(A_imag + (size_t)row * 128))[subl];
    const float4 vr = ((const float4*)W_v)[subl];        // v_re
    const float4 vi = ((const float4*)W_v)[32 + subl];   // v_im

    float p_re = ar.x*vr.x + ar.y*vr.y + ar.z*vr.z + ar.w*vr.w
               - (ai.x*vi.x + ai.y*vi.y + ai.z*vi.z + ai.w*vi.w);
    float p_im = ai.x*vr.x + ai.y*vr.y + ai.z*vr.z + ai.w*vr.w
               + ar.x*vi.x + ar.y*vi.y + ar.z*vi.z + ar.w*vi.w;

    // reduce across the 32 lanes of this row (xor masks < 32 stay in-half)
    #pragma unroll
    for (int off = 1; off < 32; off <<= 1) {
        p_re += __shfl_xor(p_re, off);
        p_im += __shfl_xor(p_im, off);
    }
    if (subl == 0) {
        h_re[row] = h_d_real[row] + p_re;
        h_im[row] = h_d_imag[row] + p_im;
    }
}

__global__ __launch_bounds__(256) void gemm_rate_kernel(
    const float* __restrict__ h_re,
    const float* __restrict__ h_im,
    const float* __restrict__ W_v,       // rows 1.. = W (1024 x 256)
    float* __restrict__ out)
{
    const int k = blockIdx.x;            // 0..127
    const int t = threadIdx.x;           // 0..255
    const int c = t & 127;               // output column
    const int half = t >> 7;             // m-range half

    __shared__ float sh_re[1024];
    __shared__ float sh_im[1024];
    // stage h row k (1024 floats each) into LDS: 256 threads x float4
    ((float4*)sh_re)[t] = ((const float4*)(h_re + (size_t)k * 1024))[t];
    ((float4*)sh_im)[t] = ((const float4*)(h_im + (size_t)k * 1024))[t];
    __syncthreads();

    float gre = 0.f, gim = 0.f;
    const float* Wbase = W_v + 256;      // skip v row; W[m,c] = Wbase[m*256+c]
    const int m0 = half * 512;
    #pragma unroll 8
    for (int m = m0; m < m0 + 512; ++m) {
        float wr = Wbase[m * 256 + c];
        float wi = Wbase[m * 256 + 128 + c];
        float hr = sh_re[m];
        float hi = sh_im[m];
        gre = fmaf(hr, wr, gre);
        gre = fmaf(-hi, wi, gre);
        gim = fmaf(hr, wi, gim);
        gim = fmaf(hi, wr, gim);
    }

    __shared__ float s_re[256], s_im[256];
    s_re[t] = gre; s_im[t] = gim;
    __syncthreads();

    __shared__ float s_wsum[2];
    __shared__ float s_sig;
    float mag = 0.f;
    if (t < 128) {
        float gr = s_re[t] + s_re[t + 128];
        float gi = s_im[t] + s_im[t + 128];
        mag = sqrtf(gr * gr + gi * gi);
        if (t == k) s_sig = mag;         // diagonal element
    }
    // sum mag over the first 128 threads (waves 0 and 1)
    float v = mag;
    #pragma unroll
    for (int off = 32; off > 0; off >>= 1) v += __shfl_xor(v, off);
    if ((t & 63) == 0 && t < 128) s_wsum[t >> 6] = v;
    __syncthreads();

    if (t == 0) {
        float total  = s_wsum[0] + s_wsum[1];
        float sig    = s_sig;
        float interf = total - sig;
        float R      = sig / (interf + 1e-11f);   // N0 = 10^(-80/10)/1000
        atomicAdd(out, -R * 1e6f);
    }
}

extern "C" void kernel_launch(void* const* d_in, const int* in_sizes, int n_in,
                              void* d_out, int out_size, void* d_ws, size_t ws_size,
                              hipStream_t stream) {
    const float* W_v      = (const float*)d_in[0];
    const float* A_real   = (const float*)d_in[1];
    const float* A_imag   = (const float*)d_in[2];
    const float* h_d_real = (const float*)d_in[3];
    const float* h_d_imag = (const float*)d_in[4];
    float* out  = (float*)d_out;
    float* h_re = (float*)d_ws;                // 131072 floats
    float* h_im = h_re + KM_ROWS;              // 131072 floats (1 MB total)

    hipMemsetAsync(d_out, 0, sizeof(float), stream);   // out is poisoned each launch

    // 131072 rows / (2 rows per wave * 4 waves per block) = 16384 blocks
    compute_h_kernel<<<16384, 256, 0, stream>>>(A_real, A_imag, W_v,
                                                h_d_real, h_d_imag, h_re, h_im);
    gemm_rate_kernel<<<128, 256, 0, stream>>>(h_re, h_im, W_v, out);
}

// Round 2
// 166.815 us; speedup vs baseline: 1.1425x; 1.1425x over previous
//
#include <hip/hip_runtime.h>

// K=128 users, M=1024, N=C=128.
// k1 (HBM-bound, 134 MB): h[k,m] = h_d[k,m] + sum_n A[k,m,n]*v[n]  (complex)
// k2 (L2-bound ~128MB L2 traffic): partial g = h @ W over 8 m-slices
// k3 (tiny): reduce partials -> mag -> SINR -> atomicAdd

#define KM_ROWS (128 * 1024)

__device__ __forceinline__ float dot4(float4 a, float4 b) {
    return a.x*b.x + a.y*b.y + a.z*b.z + a.w*b.w;
}

__global__ __launch_bounds__(256) void compute_h_kernel(
    const float* __restrict__ A_real,
    const float* __restrict__ A_imag,
    const float* __restrict__ W_v,       // row 0 = v (256 floats: v_re | v_im)
    const float* __restrict__ h_d_real,
    const float* __restrict__ h_d_imag,
    float* __restrict__ h_re,
    float* __restrict__ h_im)
{
    const int lane = threadIdx.x & 63;
    const int sub  = lane & 15;          // chunk within row (16 lanes/row)
    const int rsub = lane >> 4;          // row within wave group (0..3)
    const int wid  = blockIdx.x * 4 + (threadIdx.x >> 6);
    const int nw   = gridDim.x * 4;

    // v chunks for this lane (row 0 of W_v): re = float4[0..31], im = [32..63]
    const float4 vr0 = ((const float4*)W_v)[sub];
    const float4 vr1 = ((const float4*)W_v)[sub + 16];
    const float4 vi0 = ((const float4*)W_v)[32 + sub];
    const float4 vi1 = ((const float4*)W_v)[48 + sub];

    for (int base = wid; base < KM_ROWS / 4; base += nw) {
        const int row = base * 4 + rsub;
        const float4* Ar = (const float4*)(A_real + (size_t)row * 128);
        const float4* Ai = (const float4*)(A_imag + (size_t)row * 128);
        // 4 independent 16B loads in flight per lane
        const float4 a0 = Ar[sub];
        const float4 a1 = Ar[sub + 16];
        const float4 b0 = Ai[sub];
        const float4 b1 = Ai[sub + 16];

        float p_re = dot4(a0, vr0) + dot4(a1, vr1) - dot4(b0, vi0) - dot4(b1, vi1);
        float p_im = dot4(b0, vr0) + dot4(b1, vr1) + dot4(a0, vi0) + dot4(a1, vi1);

        #pragma unroll
        for (int off = 1; off < 16; off <<= 1) {
            p_re += __shfl_xor(p_re, off);
            p_im += __shfl_xor(p_im, off);
        }
        if (sub == 0) {
            h_re[row] = h_d_real[row] + p_re;
            h_im[row] = h_d_imag[row] + p_im;
        }
    }
}

__global__ __launch_bounds__(256) void gemm_partial_kernel(
    const float* __restrict__ h_re,
    const float* __restrict__ h_im,
    const float* __restrict__ W_v,       // rows 1.. = W (1024 x 256)
    float* __restrict__ part_re,         // [8][128][128] = [slice][k][c]
    float* __restrict__ part_im)
{
    const int k     = blockIdx.x >> 3;   // 0..127
    const int slice = blockIdx.x & 7;    // 0..7 (m-slice of 128)
    const int t = threadIdx.x;           // 0..255
    const int c = t & 127;               // output column
    const int half = t >> 7;             // m-subrange (64 each)

    __shared__ float sh_re[128], sh_im[128];
    if (t < 128) {
        sh_re[t] = h_re[k * 1024 + slice * 128 + t];
        sh_im[t] = h_im[k * 1024 + slice * 128 + t];
    }
    __syncthreads();

    const float* Wb = W_v + 256 + (size_t)(slice * 128) * 256; // W[slice*128 + m][*]
    float gre = 0.f, gim = 0.f;
    const int m0 = half * 64;
    #pragma unroll 8
    for (int m = m0; m < m0 + 64; ++m) {
        float wr = Wb[m * 256 + c];
        float wi = Wb[m * 256 + 128 + c];
        float hr = sh_re[m];
        float hi = sh_im[m];
        gre = fmaf(hr, wr, gre);
        gre = fmaf(-hi, wi, gre);
        gim = fmaf(hr, wi, gim);
        gim = fmaf(hi, wr, gim);
    }

    __shared__ float s_re[256], s_im[256];
    s_re[t] = gre; s_im[t] = gim;
    __syncthreads();
    if (t < 128) {
        const int idx = (slice * 128 + k) * 128 + t;
        part_re[idx] = s_re[t] + s_re[t + 128];
        part_im[idx] = s_im[t] + s_im[t + 128];
    }
}

__global__ __launch_bounds__(128) void rate_kernel(
    const float* __restrict__ part_re,
    const float* __restrict__ part_im,
    float* __restrict__ out)
{
    const int k = blockIdx.x;    // 0..127
    const int c = threadIdx.x;   // 0..127

    float gr = 0.f, gi = 0.f;
    #pragma unroll
    for (int s = 0; s < 8; ++s) {
        gr += part_re[(s * 128 + k) * 128 + c];
        gi += part_im[(s * 128 + k) * 128 + c];
    }
    float mag = sqrtf(gr * gr + gi * gi);

    __shared__ float s_sig;
    __shared__ float s_w[2];
    if (c == k) s_sig = mag;

    float v = mag;
    #pragma unroll
    for (int off = 32; off > 0; off >>= 1) v += __shfl_xor(v, off);
    if ((c & 63) == 0) s_w[c >> 6] = v;
    __syncthreads();

    if (c == 0) {
        float total  = s_w[0] + s_w[1];
        float interf = total - s_sig;
        float R      = s_sig / (interf + 1e-11f);   // N0 = 10^(-80/10)/1000
        atomicAdd(out, -R * 1e6f);
    }
}

extern "C" void kernel_launch(void* const* d_in, const int* in_sizes, int n_in,
                              void* d_out, int out_size, void* d_ws, size_t ws_size,
                              hipStream_t stream) {
    const float* W_v      = (const float*)d_in[0];
    const float* A_real   = (const float*)d_in[1];
    const float* A_imag   = (const float*)d_in[2];
    const float* h_d_real = (const float*)d_in[3];
    const float* h_d_imag = (const float*)d_in[4];
    float* out  = (float*)d_out;

    float* h_re    = (float*)d_ws;          // 131072 floats
    float* h_im    = h_re + KM_ROWS;        // 131072 floats
    float* part_re = h_im + KM_ROWS;        // 8*128*128 = 131072 floats
    float* part_im = part_re + 8 * 128 * 128;

    hipMemsetAsync(d_out, 0, sizeof(float), stream);

    // 2048 blocks * 4 waves = 8192 waves; 4 rows/wave/iter; 4 iters each
    compute_h_kernel<<<2048, 256, 0, stream>>>(A_real, A_imag, W_v,
                                               h_d_real, h_d_imag, h_re, h_im);
    // 128 k * 8 m-slices = 1024 blocks
    gemm_partial_kernel<<<1024, 256, 0, stream>>>(h_re, h_im, W_v, part_re, part_im);
    rate_kernel<<<128, 128, 0, stream>>>(part_re, part_im, out);
}

// Round 3
// 163.785 us; speedup vs baseline: 1.1637x; 1.0185x over previous
//
#include <hip/hip_runtime.h>

// K=128 users, M=1024, N=C=128.
// k1 (134 MB streamed): h[k,m] = h_d[k,m] + sum_n A[k,m,n]*v[n]  (complex)
//     ILP-restructured: 8 rows/wave/iter, 8 loads in flight per lane,
//     two interleaved shuffle-reduction trees.
// k2: partial g = h @ W over 8 m-slices, float4 W loads
// k3 (tiny): reduce partials -> mag -> SINR -> atomicAdd

#define KM_ROWS (128 * 1024)

__device__ __forceinline__ float dot4(float4 a, float4 b) {
    return a.x*b.x + a.y*b.y + a.z*b.z + a.w*b.w;
}

__global__ __launch_bounds__(256) void compute_h_kernel(
    const float* __restrict__ A_real,
    const float* __restrict__ A_imag,
    const float* __restrict__ W_v,       // row 0 = v (256 floats: v_re | v_im)
    const float* __restrict__ h_d_real,
    const float* __restrict__ h_d_imag,
    float* __restrict__ h_re,
    float* __restrict__ h_im)
{
    const int lane = threadIdx.x & 63;
    const int sub  = lane & 15;          // chunk within row (16 lanes/row)
    const int rsub = lane >> 4;          // row within quad (0..3)
    const int wid  = blockIdx.x * 4 + (threadIdx.x >> 6);
    const int nw   = gridDim.x * 4;

    // v chunks (row 0 of W_v): re = float4[0..31], im = [32..63]
    const float4 vr0 = ((const float4*)W_v)[sub];
    const float4 vr1 = ((const float4*)W_v)[sub + 16];
    const float4 vi0 = ((const float4*)W_v)[32 + sub];
    const float4 vi1 = ((const float4*)W_v)[48 + sub];

    // each wave-iteration covers 8 consecutive rows (two quads)
    for (int base = wid; base < KM_ROWS / 8; base += nw) {
        const int r0 = base * 8 + rsub;
        const int r1 = r0 + 4;
        const float4* Ar0 = (const float4*)(A_real + (size_t)r0 * 128);
        const float4* Ai0 = (const float4*)(A_imag + (size_t)r0 * 128);
        const float4* Ar1 = (const float4*)(A_real + (size_t)r1 * 128);
        const float4* Ai1 = (const float4*)(A_imag + (size_t)r1 * 128);

        // 8 independent 16B loads in flight per lane
        const float4 a0 = Ar0[sub];
        const float4 a1 = Ar0[sub + 16];
        const float4 b0 = Ai0[sub];
        const float4 b1 = Ai0[sub + 16];
        const float4 c0 = Ar1[sub];
        const float4 c1 = Ar1[sub + 16];
        const float4 d0 = Ai1[sub];
        const float4 d1 = Ai1[sub + 16];

        // h_d loads early too (broadcast within the 16-lane group)
        const float hdr0 = h_d_real[r0], hdi0 = h_d_imag[r0];
        const float hdr1 = h_d_real[r1], hdi1 = h_d_imag[r1];

        float p_re = dot4(a0, vr0) + dot4(a1, vr1) - dot4(b0, vi0) - dot4(b1, vi1);
        float p_im = dot4(b0, vr0) + dot4(b1, vr1) + dot4(a0, vi0) + dot4(a1, vi1);
        float q_re = dot4(c0, vr0) + dot4(c1, vr1) - dot4(d0, vi0) - dot4(d1, vi1);
        float q_im = dot4(d0, vr0) + dot4(d1, vr1) + dot4(c0, vi0) + dot4(c1, vi1);

        // two independent 4-step reduction trees, interleaved
        #pragma unroll
        for (int off = 1; off < 16; off <<= 1) {
            p_re += __shfl_xor(p_re, off);
            p_im += __shfl_xor(p_im, off);
            q_re += __shfl_xor(q_re, off);
            q_im += __shfl_xor(q_im, off);
        }
        if (sub == 0) {
            h_re[r0] = hdr0 + p_re;
            h_im[r0] = hdi0 + p_im;
            h_re[r1] = hdr1 + q_re;
            h_im[r1] = hdi1 + q_im;
        }
    }
}

__global__ __launch_bounds__(256) void gemm_partial_kernel(
    const float* __restrict__ h_re,
    const float* __restrict__ h_im,
    const float* __restrict__ W_v,       // rows 1.. = W (1024 x 256)
    float* __restrict__ part_re,         // [8][128][128] = [slice][k][c]
    float* __restrict__ part_im)
{
    const int k     = blockIdx.x >> 3;   // 0..127
    const int slice = blockIdx.x & 7;    // 0..7 (m-slice of 128)
    const int t  = threadIdx.x;          // 0..255
    const int c4 = t & 31;               // column group (4 cols each)
    const int seg = t >> 5;              // m-subrange (16 rows each)

    __shared__ float sh_re[128], sh_im[128];
    if (t < 128) {
        sh_re[t] = h_re[k * 1024 + slice * 128 + t];
        sh_im[t] = h_im[k * 1024 + slice * 128 + t];
    }
    __syncthreads();

    const float* Wb = W_v + 256 + (size_t)(slice * 128) * 256;
    float4 gre = {0.f, 0.f, 0.f, 0.f};
    float4 gim = {0.f, 0.f, 0.f, 0.f};
    const int m0 = seg * 16;
    #pragma unroll 4
    for (int m = m0; m < m0 + 16; ++m) {
        const float4* Wr4 = (const float4*)(Wb + m * 256);
        float4 wr = Wr4[c4];
        float4 wi = Wr4[c4 + 32];
        float hr = sh_re[m];
        float hi = sh_im[m];
        gre.x = fmaf(hr, wr.x, gre.x); gre.x = fmaf(-hi, wi.x, gre.x);
        gre.y = fmaf(hr, wr.y, gre.y); gre.y = fmaf(-hi, wi.y, gre.y);
        gre.z = fmaf(hr, wr.z, gre.z); gre.z = fmaf(-hi, wi.z, gre.z);
        gre.w = fmaf(hr, wr.w, gre.w); gre.w = fmaf(-hi, wi.w, gre.w);
        gim.x = fmaf(hr, wi.x, gim.x); gim.x = fmaf(hi, wr.x, gim.x);
        gim.y = fmaf(hr, wi.y, gim.y); gim.y = fmaf(hi, wr.y, gim.y);
        gim.z = fmaf(hr, wi.z, gim.z); gim.z = fmaf(hi, wr.z, gim.z);
        gim.w = fmaf(hr, wi.w, gim.w); gim.w = fmaf(hi, wr.w, gim.w);
    }

    __shared__ float4 s_re[256], s_im[256];
    s_re[t] = gre; s_im[t] = gim;
    __syncthreads();
    if (t < 32) {
        float4 r = s_re[t], i = s_im[t];
        #pragma unroll
        for (int s = 1; s < 8; ++s) {
            float4 rr = s_re[s * 32 + t], ii = s_im[s * 32 + t];
            r.x += rr.x; r.y += rr.y; r.z += rr.z; r.w += rr.w;
            i.x += ii.x; i.y += ii.y; i.z += ii.z; i.w += ii.w;
        }
        float4* pr = (float4*)(part_re + (size_t)(slice * 128 + k) * 128);
        float4* pi = (float4*)(part_im + (size_t)(slice * 128 + k) * 128);
        pr[t] = r;
        pi[t] = i;
    }
}

__global__ __launch_bounds__(128) void rate_kernel(
    const float* __restrict__ part_re,
    const float* __restrict__ part_im,
    float* __restrict__ out)
{
    const int k = blockIdx.x;    // 0..127
    const int c = threadIdx.x;   // 0..127

    float gr = 0.f, gi = 0.f;
    #pragma unroll
    for (int s = 0; s < 8; ++s) {
        gr += part_re[(s * 128 + k) * 128 + c];
        gi += part_im[(s * 128 + k) * 128 + c];
    }
    float mag = sqrtf(gr * gr + gi * gi);

    __shared__ float s_sig;
    __shared__ float s_w[2];
    if (c == k) s_sig = mag;

    float v = mag;
    #pragma unroll
    for (int off = 32; off > 0; off >>= 1) v += __shfl_xor(v, off);
    if ((c & 63) == 0) s_w[c >> 6] = v;
    __syncthreads();

    if (c == 0) {
        float total  = s_w[0] + s_w[1];
        float interf = total - s_sig;
        float R      = s_sig / (interf + 1e-11f);   // N0 = 10^(-80/10)/1000
        atomicAdd(out, -R * 1e6f);
    }
}

extern "C" void kernel_launch(void* const* d_in, const int* in_sizes, int n_in,
                              void* d_out, int out_size, void* d_ws, size_t ws_size,
                              hipStream_t stream) {
    const float* W_v      = (const float*)d_in[0];
    const float* A_real   = (const float*)d_in[1];
    const float* A_imag   = (const float*)d_in[2];
    const float* h_d_real = (const float*)d_in[3];
    const float* h_d_imag = (const float*)d_in[4];
    float* out  = (float*)d_out;

    float* h_re    = (float*)d_ws;          // 131072 floats
    float* h_im    = h_re + KM_ROWS;        // 131072 floats
    float* part_re = h_im + KM_ROWS;        // 8*128*128 = 131072 floats
    float* part_im = part_re + 8 * 128 * 128;

    hipMemsetAsync(d_out, 0, sizeof(float), stream);

    // 2048 blocks * 4 waves = 8192 waves; 8 rows/wave/iter; 2 iters each
    compute_h_kernel<<<2048, 256, 0, stream>>>(A_real, A_imag, W_v,
                                               h_d_real, h_d_imag, h_re, h_im);
    // 128 k * 8 m-slices = 1024 blocks
    gemm_partial_kernel<<<1024, 256, 0, stream>>>(h_re, h_im, W_v, part_re, part_im);
    rate_kernel<<<128, 128, 0, stream>>>(part_re, part_im, out);
}